// Round 1
// baseline (64.805 us; speedup 1.0000x reference)
//
#include <hip/hip_runtime.h>
#include <math.h>

// CornerBoundingBoxEMDLoss: min-cost 8x8 assignment per batch.
// Held-Karp subset DP (1024 transitions/batch) instead of the reference's
// 40320-permutation GEMM. One wave (64 lanes) per batch; dp table in LDS.

#define WAVES_PER_BLOCK 4

__global__ __launch_bounds__(256) void emd8_kernel(
    const float* __restrict__ pred,
    const float* __restrict__ targ,
    float* __restrict__ out, int B) {

    __shared__ float s_pts [WAVES_PER_BLOCK][48];   // 24 pred floats + 24 target floats
    __shared__ float s_dist[WAVES_PER_BLOCK][64];   // dist[i][j], i=pred row, j=target row
    __shared__ float s_dp  [WAVES_PER_BLOCK][256];  // dp over target subsets

    const int tid  = threadIdx.x;
    const int wave = tid >> 6;
    const int lane = tid & 63;
    const int b    = blockIdx.x * WAVES_PER_BLOCK + wave;
    const bool active = (b < B);

    // Stage this batch's 48 floats into LDS (lanes 0..47, coalesced-ish).
    if (active) {
        if (lane < 24)      s_pts[wave][lane] = pred[b * 24 + lane];
        else if (lane < 48) s_pts[wave][lane] = targ[b * 24 + (lane - 24)];
    }
    __syncthreads();

    // Each lane computes one entry of the 8x8 distance matrix.
    if (active) {
        const int i = lane >> 3;      // pred corner
        const int j = lane & 7;       // target corner
        const float dx = s_pts[wave][i * 3 + 0] - s_pts[wave][24 + j * 3 + 0];
        const float dy = s_pts[wave][i * 3 + 1] - s_pts[wave][24 + j * 3 + 1];
        const float dz = s_pts[wave][i * 3 + 2] - s_pts[wave][24 + j * 3 + 2];
        s_dist[wave][lane] = sqrtf(dx * dx + dy * dy + dz * dz);

        // dp init: dp[0]=0; everything else written before read, INF for safety.
        #pragma unroll
        for (int s = 0; s < 4; ++s) {
            const int m = lane + (s << 6);
            s_dp[wave][m] = (m == 0) ? 0.0f : 1e30f;
        }
    }
    __syncthreads();

    // Held-Karp levels: at level k, masks with popcount k assign pred row k-1.
    #pragma unroll
    for (int k = 1; k <= 8; ++k) {
        if (active) {
            #pragma unroll
            for (int s = 0; s < 4; ++s) {
                const int m = lane + (s << 6);
                if (__popc(m) == k) {
                    const float* dr = &s_dist[wave][(k - 1) * 8];
                    float best = 1e30f;
                    int mm = m;
                    while (mm) {
                        const int j = __ffs(mm) - 1;
                        mm &= (mm - 1);
                        const float c = s_dp[wave][m ^ (1 << j)] + dr[j];
                        best = fminf(best, c);
                    }
                    s_dp[wave][m] = best;   // popcount-k write, only popcount-(k-1) reads this level
                }
            }
        }
        __syncthreads();
    }

    if (active && lane == 0) out[b] = s_dp[wave][255];
}

extern "C" void kernel_launch(void* const* d_in, const int* in_sizes, int n_in,
                              void* d_out, int out_size, void* d_ws, size_t ws_size,
                              hipStream_t stream) {
    const float* pred = (const float*)d_in[0];
    const float* targ = (const float*)d_in[1];
    float* out = (float*)d_out;
    const int B = in_sizes[0] / 24;   // [B, 8, 3]
    const int grid = (B + WAVES_PER_BLOCK - 1) / WAVES_PER_BLOCK;
    emd8_kernel<<<grid, 256, 0, stream>>>(pred, targ, out, B);
}

// Round 2
// 64.132 us; speedup vs baseline: 1.0105x; 1.0105x over previous
//
#include <hip/hip_runtime.h>
#include <math.h>

// CornerBoundingBoxEMDLoss: min-cost 8x8 assignment per batch via Held-Karp
// subset DP, fully register-resident. One wave (64 lanes) per batch:
//   dp[256] = 4 VGPRs/lane, dp[lane + 64*s] in reg s.
// Transitions dp[m^(1<<j)]: j<6 -> __shfl_xor (same reg, lane^(1<<j));
// j=6/7 -> same lane, reg s^1 / s^2. No LDS, no __syncthreads.
// The popc(m)==k gate is implicit: dp is finite only at popc==k after level k,
// so invalid candidates (INF + d) lose every fminf automatically.

#define INF 1e30f
#define WAVES_PER_BLOCK 4

__global__ __launch_bounds__(256) void emd8_wave_kernel(
    const float* __restrict__ pred,
    const float* __restrict__ targ,
    float* __restrict__ out, int B) {

    const int tid  = threadIdx.x;
    const int lane = tid & 63;
    const int b    = (int)((blockIdx.x * blockDim.x + tid) >> 6);  // one batch per wave
    if (b >= B) return;  // B % 4 == 0 in practice; wave-uniform branch

    // Stage the batch's 48 floats across lanes 0..47 (contiguous 96B reads).
    float v = 0.0f;
    if (lane < 48) {
        v = (lane < 24) ? pred[b * 24 + lane] : targ[b * 24 + (lane - 24)];
    }

    // Lane (i*8+j) computes dist[i][j].
    const int i = lane >> 3, j = lane & 7;
    const float px = __shfl(v, i * 3 + 0);
    const float py = __shfl(v, i * 3 + 1);
    const float pz = __shfl(v, i * 3 + 2);
    const float tx = __shfl(v, 24 + j * 3 + 0);
    const float ty = __shfl(v, 24 + j * 3 + 1);
    const float tz = __shfl(v, 24 + j * 3 + 2);
    const float dx = px - tx, dy = py - ty, dz = pz - tz;
    const float dist = sqrtf(dx * dx + dy * dy + dz * dz);

    // dp init: dp[0] = 0 (lane 0, reg 0), else INF.
    float r0 = (lane == 0) ? 0.0f : INF;
    float r1 = INF, r2 = INF, r3 = INF;

    #pragma unroll
    for (int k = 1; k <= 8; ++k) {
        // Broadcast dist row k-1 (constant source lanes -> readlane/SGPR).
        float d[8];
        #pragma unroll
        for (int jj = 0; jj < 8; ++jj) d[jj] = __shfl(dist, (k - 1) * 8 + jj);

        float n0 = INF, n1 = INF, n2 = INF, n3 = INF;
        #pragma unroll
        for (int jj = 0; jj < 6; ++jj) {
            const float s0 = __shfl_xor(r0, 1 << jj);
            const float s1 = __shfl_xor(r1, 1 << jj);
            const float s2 = __shfl_xor(r2, 1 << jj);
            const float s3 = __shfl_xor(r3, 1 << jj);
            n0 = fminf(n0, s0 + d[jj]);
            n1 = fminf(n1, s1 + d[jj]);
            n2 = fminf(n2, s2 + d[jj]);
            n3 = fminf(n3, s3 + d[jj]);
        }
        // Mask bits 6/7 live in the reg index: j=6 flips bit0, j=7 flips bit1.
        n0 = fminf(n0, fminf(r1 + d[6], r2 + d[7]));
        n1 = fminf(n1, fminf(r0 + d[6], r3 + d[7]));
        n2 = fminf(n2, fminf(r3 + d[6], r0 + d[7]));
        n3 = fminf(n3, fminf(r2 + d[6], r1 + d[7]));
        r0 = n0; r1 = n1; r2 = n2; r3 = n3;
    }

    // Answer = dp[255] = lane 63, reg 3.
    if (lane == 63) out[b] = r3;
}

extern "C" void kernel_launch(void* const* d_in, const int* in_sizes, int n_in,
                              void* d_out, int out_size, void* d_ws, size_t ws_size,
                              hipStream_t stream) {
    const float* pred = (const float*)d_in[0];
    const float* targ = (const float*)d_in[1];
    float* out = (float*)d_out;
    const int B = in_sizes[0] / 24;                    // [B, 8, 3]
    const int waves = B;                               // one wave per batch
    const int grid  = (waves + WAVES_PER_BLOCK - 1) / WAVES_PER_BLOCK;
    emd8_wave_kernel<<<grid, 64 * WAVES_PER_BLOCK, 0, stream>>>(pred, targ, out, B);
}